// Round 1
// baseline (418.982 us; speedup 1.0000x reference)
//
#include <hip/hip_runtime.h>

#define NB 8
#define NN 4096
#define DNF 64
#define NEDGE 1048576
#define DM 64
#define FF 64

using f32x4 = __attribute__((ext_vector_type(4))) float;
using s16x8 = __attribute__((ext_vector_type(8))) short;

__device__ __forceinline__ unsigned short f2b(float f) {
    union { float f; unsigned u; } v; v.f = f;
    unsigned r = (v.u + 0x7fffu + ((v.u >> 16) & 1u)) >> 16;
    return (unsigned short)r;
}

// Pack W [K x Ncols] (f32 row-major) into MFMA B-fragment order (bf16):
// out[((nt*KS + ks)*64 + lane)*8 + j] = W[(ks*32 + (lane>>4)*8 + j)*Ncols + nt*16 + (lane&15)]
__global__ void pack_weights(const float* __restrict__ W, unsigned short* __restrict__ out,
                             int K, int Ncols) {
    int idx = blockIdx.x * 256 + threadIdx.x;
    int total = K * Ncols;
    if (idx >= total) return;
    int j = idx & 7;
    int lane = (idx >> 3) & 63;
    int frag = idx >> 9;
    int KS = K >> 5;
    int ks = frag % KS;
    int nt = frag / KS;
    int k = ks * 32 + ((lane >> 4) << 3) + j;
    int col = nt * 16 + (lane & 15);
    out[idx] = f2b(W[k * Ncols + col]);
}

// Edge kernel: 64 edges/block, 256 threads (4 waves x 16 edge-rows).
// feats(128) -> relu(W1) -> (W2) -> *edge_val -> atomic scatter into sums/counts.
__launch_bounds__(256, 4)
__global__ void edge_kernel(const float* __restrict__ node_feats,
                            const int* __restrict__ eb, const int* __restrict__ esrc,
                            const int* __restrict__ edst, const float* __restrict__ evals,
                            const unsigned short* __restrict__ W1p, const float* __restrict__ b1,
                            const unsigned short* __restrict__ W2p, const float* __restrict__ b2,
                            float* __restrict__ sums, float* __restrict__ counts) {
    __shared__ unsigned short A1[64][136];
    __shared__ unsigned short Hs[64][136];
    const int tid = threadIdx.x;
    const int e0 = blockIdx.x * 64;

    // counts: one +1 per edge
    if (tid < 64) {
        int e = e0 + tid;
        atomicAdd(&counts[eb[e] * NN + esrc[e]], 1.0f);
    }

    // gather: 64 edges x 128 feats (src|dst), 2 elems/thread/iter
    for (int i = 0; i < 16; ++i) {
        int idx = i * 256 + tid;          // 0..4095
        int edge = idx >> 6;              // 0..63
        int p = idx & 63;                 // pair index -> elems 2p,2p+1
        int e = e0 + edge;
        int b = eb[e];
        const float* row;
        if (p < 32) row = node_feats + ((size_t)b * NN + esrc[e]) * DNF;
        else        row = node_feats + ((size_t)b * NN + edst[e]) * DNF - 64;
        float2 v = *reinterpret_cast<const float2*>(row + 2 * p);
        unsigned packed = (unsigned)f2b(v.x) | ((unsigned)f2b(v.y) << 16);
        *reinterpret_cast<unsigned*>(&A1[edge][2 * p]) = packed;
    }
    __syncthreads();

    const int wave = tid >> 6;
    const int lane = tid & 63;
    const int lr = lane & 15;   // A-row / B-col / D-col
    const int lq = lane >> 4;
    const int arow = wave * 16 + lr;

    // layer 1: [16x128] @ [128x128] -> relu -> Hs (bf16)
    s16x8 a[4];
#pragma unroll
    for (int ks = 0; ks < 4; ++ks)
        a[ks] = *reinterpret_cast<const s16x8*>(&A1[arow][ks * 32 + lq * 8]);
#pragma unroll
    for (int nt = 0; nt < 8; ++nt) {
        f32x4 acc = {0.f, 0.f, 0.f, 0.f};
#pragma unroll
        for (int ks = 0; ks < 4; ++ks) {
            s16x8 bf = *reinterpret_cast<const s16x8*>(&W1p[(((nt << 2) + ks) * 64 + lane) * 8]);
            acc = __builtin_amdgcn_mfma_f32_16x16x32_bf16(a[ks], bf, acc, 0, 0, 0);
        }
        float bias = b1[nt * 16 + lr];
#pragma unroll
        for (int j = 0; j < 4; ++j) {
            float h = acc[j] + bias;
            h = h > 0.f ? h : 0.f;
            Hs[wave * 16 + lq * 4 + j][nt * 16 + lr] = f2b(h);
        }
    }
    // same-wave LDS write->read: in-order, no barrier needed

    // layer 2: [16x128] @ [128x64] -> * edge_val -> atomic scatter
    s16x8 a2[4];
#pragma unroll
    for (int ks = 0; ks < 4; ++ks)
        a2[ks] = *reinterpret_cast<const s16x8*>(&Hs[arow][ks * 32 + lq * 8]);

    float ev[4]; int seg4[4];
#pragma unroll
    for (int j = 0; j < 4; ++j) {
        int r = e0 + wave * 16 + lq * 4 + j;
        ev[j] = evals[r];
        seg4[j] = eb[r] * NN + esrc[r];
    }
#pragma unroll
    for (int nt = 0; nt < 4; ++nt) {
        f32x4 acc = {0.f, 0.f, 0.f, 0.f};
#pragma unroll
        for (int ks = 0; ks < 4; ++ks) {
            s16x8 bf = *reinterpret_cast<const s16x8*>(&W2p[(((nt << 2) + ks) * 64 + lane) * 8]);
            acc = __builtin_amdgcn_mfma_f32_16x16x32_bf16(a2[ks], bf, acc, 0, 0, 0);
        }
        float bias = b2[nt * 16 + lr];
#pragma unroll
        for (int j = 0; j < 4; ++j) {
            float m = (acc[j] + bias) * ev[j];
            atomicAdd(&sums[(size_t)seg4[j] * DM + nt * 16 + lr], m);
        }
    }
}

// Node kernel: 64 nodes/block. upd_in = [node_feats | sums/max(counts,1)],
// relu(Wu1) -> Wu2 -> out. sums aliases d_out: read rows before overwrite (row-disjoint per block).
__launch_bounds__(256, 4)
__global__ void node_kernel(const float* __restrict__ node_feats,
                            const float* __restrict__ sums, const float* __restrict__ counts,
                            const unsigned short* __restrict__ W1p, const float* __restrict__ b1,
                            const unsigned short* __restrict__ W2p, const float* __restrict__ b2,
                            float* __restrict__ out) {
    __shared__ unsigned short A1[64][136];
    __shared__ unsigned short Hs[64][136];
    const int tid = threadIdx.x;
    const int g0 = blockIdx.x * 64;

    for (int i = 0; i < 16; ++i) {
        int idx = i * 256 + tid;
        int node = idx >> 6;
        int p = idx & 63;
        int g = g0 + node;
        float2 v;
        if (p < 32) {
            v = *reinterpret_cast<const float2*>(node_feats + (size_t)g * DNF + 2 * p);
        } else {
            float scale = 1.0f / fmaxf(counts[g], 1.0f);
            float2 s = *reinterpret_cast<const float2*>(sums + (size_t)g * DM + 2 * p - 64);
            v.x = s.x * scale; v.y = s.y * scale;
        }
        unsigned packed = (unsigned)f2b(v.x) | ((unsigned)f2b(v.y) << 16);
        *reinterpret_cast<unsigned*>(&A1[node][2 * p]) = packed;
    }
    __syncthreads();

    const int wave = tid >> 6;
    const int lane = tid & 63;
    const int lr = lane & 15;
    const int lq = lane >> 4;
    const int arow = wave * 16 + lr;

    s16x8 a[4];
#pragma unroll
    for (int ks = 0; ks < 4; ++ks)
        a[ks] = *reinterpret_cast<const s16x8*>(&A1[arow][ks * 32 + lq * 8]);
#pragma unroll
    for (int nt = 0; nt < 8; ++nt) {
        f32x4 acc = {0.f, 0.f, 0.f, 0.f};
#pragma unroll
        for (int ks = 0; ks < 4; ++ks) {
            s16x8 bf = *reinterpret_cast<const s16x8*>(&W1p[(((nt << 2) + ks) * 64 + lane) * 8]);
            acc = __builtin_amdgcn_mfma_f32_16x16x32_bf16(a[ks], bf, acc, 0, 0, 0);
        }
        float bias = b1[nt * 16 + lr];
#pragma unroll
        for (int j = 0; j < 4; ++j) {
            float h = acc[j] + bias;
            h = h > 0.f ? h : 0.f;
            Hs[wave * 16 + lq * 4 + j][nt * 16 + lr] = f2b(h);
        }
    }

    s16x8 a2[4];
#pragma unroll
    for (int ks = 0; ks < 4; ++ks)
        a2[ks] = *reinterpret_cast<const s16x8*>(&Hs[arow][ks * 32 + lq * 8]);
#pragma unroll
    for (int nt = 0; nt < 4; ++nt) {
        f32x4 acc = {0.f, 0.f, 0.f, 0.f};
#pragma unroll
        for (int ks = 0; ks < 4; ++ks) {
            s16x8 bf = *reinterpret_cast<const s16x8*>(&W2p[(((nt << 2) + ks) * 64 + lane) * 8]);
            acc = __builtin_amdgcn_mfma_f32_16x16x32_bf16(a2[ks], bf, acc, 0, 0, 0);
        }
        float bias = b2[nt * 16 + lr];
#pragma unroll
        for (int j = 0; j < 4; ++j) {
            int g = g0 + wave * 16 + lq * 4 + j;
            out[(size_t)g * FF + nt * 16 + lr] = acc[j] + bias;
        }
    }
}

extern "C" void kernel_launch(void* const* d_in, const int* in_sizes, int n_in,
                              void* d_out, int out_size, void* d_ws, size_t ws_size,
                              hipStream_t stream) {
    const float* node_feats = (const float*)d_in[0];
    const int*   eb    = (const int*)d_in[1];
    const int*   esrc  = (const int*)d_in[2];
    const int*   edst  = (const int*)d_in[3];
    const float* evals = (const float*)d_in[4];
    const float* Wm1 = (const float*)d_in[5];
    const float* bm1 = (const float*)d_in[6];
    const float* Wm2 = (const float*)d_in[7];
    const float* bm2 = (const float*)d_in[8];
    const float* Wu1 = (const float*)d_in[9];
    const float* bu1 = (const float*)d_in[10];
    const float* Wu2 = (const float*)d_in[11];
    const float* bu2 = (const float*)d_in[12];

    float* out = (float*)d_out;               // doubles as sums (B*N*DM == out_size)
    char* ws = (char*)d_ws;
    float* counts          = (float*)ws;                       // 32768 f32 = 128 KB
    unsigned short* W1p    = (unsigned short*)(ws + 131072);   // 32 KB
    unsigned short* W2p    = (unsigned short*)(ws + 163840);   // 16 KB
    unsigned short* Wu1p   = (unsigned short*)(ws + 180224);   // 32 KB
    unsigned short* Wu2p   = (unsigned short*)(ws + 212992);   // 16 KB

    hipMemsetAsync(d_out, 0, (size_t)out_size * sizeof(float), stream);
    hipMemsetAsync(counts, 0, 32768 * sizeof(float), stream);

    pack_weights<<<64, 256, 0, stream>>>(Wm1, W1p, 128, 128);
    pack_weights<<<32, 256, 0, stream>>>(Wm2, W2p, 128, 64);
    pack_weights<<<64, 256, 0, stream>>>(Wu1, Wu1p, 128, 128);
    pack_weights<<<32, 256, 0, stream>>>(Wu2, Wu2p, 128, 64);

    edge_kernel<<<NEDGE / 64, 256, 0, stream>>>(node_feats, eb, esrc, edst, evals,
                                                W1p, bm1, W2p, bm2, out, counts);
    node_kernel<<<(NB * NN) / 64, 256, 0, stream>>>(node_feats, out, counts,
                                                    Wu1p, bu1, Wu2p, bu2, out);
}

// Round 2
// 231.482 us; speedup vs baseline: 1.8100x; 1.8100x over previous
//
#include <hip/hip_runtime.h>
#include <hip/hip_fp16.h>

#define NB 8
#define NN 4096
#define DNF 64
#define NEDGE 1048576
#define DM 64
#define FF 64

using f32x4 = __attribute__((ext_vector_type(4))) float;
using s16x8 = __attribute__((ext_vector_type(8))) short;

__device__ __forceinline__ unsigned short f2b(float f) {
    union { float f; unsigned u; } v; v.f = f;
    unsigned r = (v.u + 0x7fffu + ((v.u >> 16) & 1u)) >> 16;
    return (unsigned short)r;
}
__device__ __forceinline__ float b2f(unsigned short b) {
    union { unsigned u; float f; } v; v.u = ((unsigned)b) << 16;
    return v.f;
}

// Pack W [K x Ncols] (f32 row-major) into MFMA B-fragment order (bf16):
// out[((nt*KS + ks)*64 + lane)*8 + j] = W[(ks*32 + (lane>>4)*8 + j)*Ncols + nt*16 + (lane&15)]
__global__ void pack_weights(const float* __restrict__ W, unsigned short* __restrict__ out,
                             int K, int Ncols) {
    int idx = blockIdx.x * 256 + threadIdx.x;
    int total = K * Ncols;
    if (idx >= total) return;
    int j = idx & 7;
    int lane = (idx >> 3) & 63;
    int frag = idx >> 9;
    int KS = K >> 5;
    int ks = frag % KS;
    int nt = frag / KS;
    int k = ks * 32 + ((lane >> 4) << 3) + j;
    int col = nt * 16 + (lane & 15);
    out[idx] = f2b(W[k * Ncols + col]);
}

// ---------------- NEW PATH ----------------

// Q = X @ Wm1[0:64,:], P = X @ Wm1[64:128,:]  (both 32768 x 128, bf16 out)
__launch_bounds__(256, 4)
__global__ void precompute_pq(const float* __restrict__ X,
                              const unsigned short* __restrict__ Qw,
                              const unsigned short* __restrict__ Pw,
                              unsigned short* __restrict__ Qp,
                              unsigned short* __restrict__ Pp) {
    __shared__ unsigned short A[64][72];
    const int tid = threadIdx.x;
    const int g0 = blockIdx.x * 64;
    for (int i = 0; i < 16; ++i) {
        int idx = i * 256 + tid;
        int node = idx >> 6;
        int f = idx & 63;
        A[node][f] = f2b(X[(size_t)(g0 + node) * DNF + f]);
    }
    __syncthreads();
    const int wave = tid >> 6, lane = tid & 63;
    const int lr = lane & 15, lq = lane >> 4;
    const int arow = wave * 16 + lr;
    s16x8 a[2];
#pragma unroll
    for (int ks = 0; ks < 2; ++ks)
        a[ks] = *reinterpret_cast<const s16x8*>(&A[arow][ks * 32 + lq * 8]);
#pragma unroll
    for (int nt = 0; nt < 8; ++nt) {
        f32x4 accQ = {0.f, 0.f, 0.f, 0.f};
        f32x4 accP = {0.f, 0.f, 0.f, 0.f};
#pragma unroll
        for (int ks = 0; ks < 2; ++ks) {
            s16x8 bq = *reinterpret_cast<const s16x8*>(&Qw[(((nt << 1) + ks) * 64 + lane) * 8]);
            s16x8 bp = *reinterpret_cast<const s16x8*>(&Pw[(((nt << 1) + ks) * 64 + lane) * 8]);
            accQ = __builtin_amdgcn_mfma_f32_16x16x32_bf16(a[ks], bq, accQ, 0, 0, 0);
            accP = __builtin_amdgcn_mfma_f32_16x16x32_bf16(a[ks], bp, accP, 0, 0, 0);
        }
#pragma unroll
        for (int j = 0; j < 4; ++j) {
            int row = g0 + wave * 16 + lq * 4 + j;
            int col = nt * 16 + lr;
            Qp[(size_t)row * 128 + col] = f2b(accQ[j]);
            Pp[(size_t)row * 128 + col] = f2b(accP[j]);
        }
    }
}

__global__ void hist_kernel(const int* __restrict__ eb, const int* __restrict__ esrc,
                            unsigned* __restrict__ hist) {
    int e = blockIdx.x * 256 + threadIdx.x;
    atomicAdd(&hist[eb[e] * NN + esrc[e]], 1u);
}

// exclusive scan over 32768 bins; writes offs[0..32768] and cursor copy
__launch_bounds__(1024)
__global__ void scan_kernel(const unsigned* __restrict__ hist,
                            unsigned* __restrict__ offs, unsigned* __restrict__ curs) {
    __shared__ unsigned part[1024];
    int t = threadIdx.x;
    unsigned v[32];
    unsigned s = 0;
#pragma unroll
    for (int i = 0; i < 32; ++i) { v[i] = hist[t * 32 + i]; s += v[i]; }
    part[t] = s;
    __syncthreads();
    for (int off = 1; off < 1024; off <<= 1) {
        unsigned x = (t >= off) ? part[t - off] : 0u;
        __syncthreads();
        part[t] += x;
        __syncthreads();
    }
    unsigned run = (t > 0) ? part[t - 1] : 0u;
#pragma unroll
    for (int i = 0; i < 32; ++i) {
        offs[t * 32 + i] = run;
        curs[t * 32 + i] = run;
        run += v[i];
    }
    if (t == 1023) offs[32768] = run;
}

__global__ void scatter_kernel(const int* __restrict__ eb, const int* __restrict__ esrc,
                               const int* __restrict__ edst, const float* __restrict__ evals,
                               unsigned* __restrict__ curs, unsigned* __restrict__ payload) {
    int e = blockIdx.x * 256 + threadIdx.x;
    int seg = eb[e] * NN + esrc[e];
    unsigned pos = atomicAdd(&curs[seg], 1u);
    unsigned short wb = __half_as_ushort(__float2half_rn(evals[e]));
    payload[pos] = (unsigned)edst[e] | ((unsigned)wb << 16);
}

// one wave per segment: s = sum_e w*relu(Q[src]+P[dst]+b1); gathered = (s@Wm2 + sumw*b2)/max(cnt,1)
__launch_bounds__(256, 4)
__global__ void segment_kernel(const unsigned short* __restrict__ Qp,
                               const unsigned short* __restrict__ Pp,
                               const unsigned* __restrict__ payload,
                               const unsigned* __restrict__ offs,
                               const float* __restrict__ Wm2, const float* __restrict__ b1,
                               const float* __restrict__ b2, float* __restrict__ gathered) {
    __shared__ unsigned short w2[128 * 64];
    __shared__ float s_lds[4][128];
    const int tid = threadIdx.x;
#pragma unroll
    for (int i = 0; i < 32; ++i) {
        int idx = i * 256 + tid;
        w2[idx] = f2b(Wm2[idx]);
    }
    __syncthreads();

    const int wv = tid >> 6, lane = tid & 63;
    const int seg = blockIdx.x * 4 + wv;
    const unsigned start = offs[seg], end = offs[seg + 1];
    const int rowbase = (seg >> 12) << 12;   // b * NN

    unsigned qv = reinterpret_cast<const unsigned*>(Qp)[(size_t)seg * 64 + lane];
    float q0 = b2f((unsigned short)(qv & 0xffff));
    float q1 = b2f((unsigned short)(qv >> 16));
    float2 bb = reinterpret_cast<const float2*>(b1)[lane];
    const unsigned* P32 = reinterpret_cast<const unsigned*>(Pp);

    float acc0 = 0.f, acc1 = 0.f, sumw = 0.f;
    for (unsigned base = start; base < end; base += 64) {
        int m = (int)min(64u, end - base);
        unsigned pay = (base + (unsigned)lane < end) ? payload[base + lane] : 0u;
        unsigned cur = __shfl(pay, 0);
        unsigned pv = P32[(size_t)(rowbase + (int)(cur & 0xFFFFu)) * 64 + lane];
        for (int i = 0; i < m; ++i) {
            unsigned pvc = pv;
            unsigned curc = cur;
            if (i + 1 < m) {
                cur = __shfl(pay, i + 1);
                pv = P32[(size_t)(rowbase + (int)(cur & 0xFFFFu)) * 64 + lane];
            }
            float w = __half2float(__ushort_as_half((unsigned short)(curc >> 16)));
            float p0 = b2f((unsigned short)(pvc & 0xffff));
            float p1 = b2f((unsigned short)(pvc >> 16));
            float h0 = fmaxf(q0 + p0 + bb.x, 0.f);
            float h1 = fmaxf(q1 + p1 + bb.y, 0.f);
            acc0 = fmaf(w, h0, acc0);
            acc1 = fmaf(w, h1, acc1);
            sumw += w;
        }
    }
    s_lds[wv][2 * lane] = acc0;
    s_lds[wv][2 * lane + 1] = acc1;
    float o = 0.f;
#pragma unroll 8
    for (int k = 0; k < 128; ++k)
        o = fmaf(s_lds[wv][k], b2f(w2[k * 64 + lane]), o);
    unsigned cnt = end - start;
    float inv = 1.0f / (float)max(cnt, 1u);
    gathered[(size_t)seg * 64 + lane] = (o + sumw * b2[lane]) * inv;
}

// ---------------- SHARED / FALLBACK KERNELS ----------------

__launch_bounds__(256, 4)
__global__ void edge_kernel(const float* __restrict__ node_feats,
                            const int* __restrict__ eb, const int* __restrict__ esrc,
                            const int* __restrict__ edst, const float* __restrict__ evals,
                            const unsigned short* __restrict__ W1p, const float* __restrict__ b1,
                            const unsigned short* __restrict__ W2p, const float* __restrict__ b2,
                            float* __restrict__ sums, float* __restrict__ counts) {
    __shared__ unsigned short A1[64][136];
    __shared__ unsigned short Hs[64][136];
    const int tid = threadIdx.x;
    const int e0 = blockIdx.x * 64;
    if (tid < 64) {
        int e = e0 + tid;
        atomicAdd(&counts[eb[e] * NN + esrc[e]], 1.0f);
    }
    for (int i = 0; i < 16; ++i) {
        int idx = i * 256 + tid;
        int edge = idx >> 6;
        int p = idx & 63;
        int e = e0 + edge;
        int b = eb[e];
        const float* row;
        if (p < 32) row = node_feats + ((size_t)b * NN + esrc[e]) * DNF;
        else        row = node_feats + ((size_t)b * NN + edst[e]) * DNF - 64;
        float2 v = *reinterpret_cast<const float2*>(row + 2 * p);
        unsigned packed = (unsigned)f2b(v.x) | ((unsigned)f2b(v.y) << 16);
        *reinterpret_cast<unsigned*>(&A1[edge][2 * p]) = packed;
    }
    __syncthreads();
    const int wave = tid >> 6, lane = tid & 63;
    const int lr = lane & 15, lq = lane >> 4;
    const int arow = wave * 16 + lr;
    s16x8 a[4];
#pragma unroll
    for (int ks = 0; ks < 4; ++ks)
        a[ks] = *reinterpret_cast<const s16x8*>(&A1[arow][ks * 32 + lq * 8]);
#pragma unroll
    for (int nt = 0; nt < 8; ++nt) {
        f32x4 acc = {0.f, 0.f, 0.f, 0.f};
#pragma unroll
        for (int ks = 0; ks < 4; ++ks) {
            s16x8 bf = *reinterpret_cast<const s16x8*>(&W1p[(((nt << 2) + ks) * 64 + lane) * 8]);
            acc = __builtin_amdgcn_mfma_f32_16x16x32_bf16(a[ks], bf, acc, 0, 0, 0);
        }
        float bias = b1[nt * 16 + lr];
#pragma unroll
        for (int j = 0; j < 4; ++j) {
            float h = acc[j] + bias;
            h = h > 0.f ? h : 0.f;
            Hs[wave * 16 + lq * 4 + j][nt * 16 + lr] = f2b(h);
        }
    }
    s16x8 a2[4];
#pragma unroll
    for (int ks = 0; ks < 4; ++ks)
        a2[ks] = *reinterpret_cast<const s16x8*>(&Hs[arow][ks * 32 + lq * 8]);
    float ev[4]; int seg4[4];
#pragma unroll
    for (int j = 0; j < 4; ++j) {
        int r = e0 + wave * 16 + lq * 4 + j;
        ev[j] = evals[r];
        seg4[j] = eb[r] * NN + esrc[r];
    }
#pragma unroll
    for (int nt = 0; nt < 4; ++nt) {
        f32x4 acc = {0.f, 0.f, 0.f, 0.f};
#pragma unroll
        for (int ks = 0; ks < 4; ++ks) {
            s16x8 bf = *reinterpret_cast<const s16x8*>(&W2p[(((nt << 2) + ks) * 64 + lane) * 8]);
            acc = __builtin_amdgcn_mfma_f32_16x16x32_bf16(a2[ks], bf, acc, 0, 0, 0);
        }
        float bias = b2[nt * 16 + lr];
#pragma unroll
        for (int j = 0; j < 4; ++j) {
            float m = (acc[j] + bias) * ev[j];
            atomicAdd(&sums[(size_t)seg4[j] * DM + nt * 16 + lr], m);
        }
    }
}

template<int SCALE>
__launch_bounds__(256, 4)
__global__ void node_kernel(const float* __restrict__ node_feats,
                            const float* __restrict__ sums, const float* __restrict__ counts,
                            const unsigned short* __restrict__ W1p, const float* __restrict__ b1,
                            const unsigned short* __restrict__ W2p, const float* __restrict__ b2,
                            float* __restrict__ out) {
    __shared__ unsigned short A1[64][136];
    __shared__ unsigned short Hs[64][136];
    const int tid = threadIdx.x;
    const int g0 = blockIdx.x * 64;
    for (int i = 0; i < 16; ++i) {
        int idx = i * 256 + tid;
        int node = idx >> 6;
        int p = idx & 63;
        int g = g0 + node;
        float2 v;
        if (p < 32) {
            v = *reinterpret_cast<const float2*>(node_feats + (size_t)g * DNF + 2 * p);
        } else {
            float2 s = *reinterpret_cast<const float2*>(sums + (size_t)g * DM + 2 * p - 64);
            if (SCALE) {
                float scale = 1.0f / fmaxf(counts[g], 1.0f);
                s.x *= scale; s.y *= scale;
            }
            v = s;
        }
        unsigned packed = (unsigned)f2b(v.x) | ((unsigned)f2b(v.y) << 16);
        *reinterpret_cast<unsigned*>(&A1[node][2 * p]) = packed;
    }
    __syncthreads();
    const int wave = tid >> 6, lane = tid & 63;
    const int lr = lane & 15, lq = lane >> 4;
    const int arow = wave * 16 + lr;
    s16x8 a[4];
#pragma unroll
    for (int ks = 0; ks < 4; ++ks)
        a[ks] = *reinterpret_cast<const s16x8*>(&A1[arow][ks * 32 + lq * 8]);
#pragma unroll
    for (int nt = 0; nt < 8; ++nt) {
        f32x4 acc = {0.f, 0.f, 0.f, 0.f};
#pragma unroll
        for (int ks = 0; ks < 4; ++ks) {
            s16x8 bf = *reinterpret_cast<const s16x8*>(&W1p[(((nt << 2) + ks) * 64 + lane) * 8]);
            acc = __builtin_amdgcn_mfma_f32_16x16x32_bf16(a[ks], bf, acc, 0, 0, 0);
        }
        float bias = b1[nt * 16 + lr];
#pragma unroll
        for (int j = 0; j < 4; ++j) {
            float h = acc[j] + bias;
            h = h > 0.f ? h : 0.f;
            Hs[wave * 16 + lq * 4 + j][nt * 16 + lr] = f2b(h);
        }
    }
    s16x8 a2[4];
#pragma unroll
    for (int ks = 0; ks < 4; ++ks)
        a2[ks] = *reinterpret_cast<const s16x8*>(&Hs[arow][ks * 32 + lq * 8]);
#pragma unroll
    for (int nt = 0; nt < 4; ++nt) {
        f32x4 acc = {0.f, 0.f, 0.f, 0.f};
#pragma unroll
        for (int ks = 0; ks < 4; ++ks) {
            s16x8 bf = *reinterpret_cast<const s16x8*>(&W2p[(((nt << 2) + ks) * 64 + lane) * 8]);
            acc = __builtin_amdgcn_mfma_f32_16x16x32_bf16(a2[ks], bf, acc, 0, 0, 0);
        }
        float bias = b2[nt * 16 + lr];
#pragma unroll
        for (int j = 0; j < 4; ++j) {
            int g = g0 + wave * 16 + lq * 4 + j;
            out[(size_t)g * FF + nt * 16 + lr] = acc[j] + bias;
        }
    }
}

extern "C" void kernel_launch(void* const* d_in, const int* in_sizes, int n_in,
                              void* d_out, int out_size, void* d_ws, size_t ws_size,
                              hipStream_t stream) {
    const float* node_feats = (const float*)d_in[0];
    const int*   eb    = (const int*)d_in[1];
    const int*   esrc  = (const int*)d_in[2];
    const int*   edst  = (const int*)d_in[3];
    const float* evals = (const float*)d_in[4];
    const float* Wm1 = (const float*)d_in[5];
    const float* bm1 = (const float*)d_in[6];
    const float* Wm2 = (const float*)d_in[7];
    const float* bm2 = (const float*)d_in[8];
    const float* Wu1 = (const float*)d_in[9];
    const float* bu1 = (const float*)d_in[10];
    const float* Wu2 = (const float*)d_in[11];
    const float* bu2 = (const float*)d_in[12];
    float* out = (float*)d_out;
    char* ws = (char*)d_ws;

    const size_t NEED = 22u * 1024 * 1024;
    if (ws_size >= NEED) {
        // ---- new path: factorized MLP + counting sort, zero f32 atomics ----
        unsigned short* Qp   = (unsigned short*)(ws);                     // 8 MB
        unsigned short* Pp   = (unsigned short*)(ws + 8388608);           // 8 MB
        unsigned*       pay  = (unsigned*)(ws + 16777216);                // 4 MB
        unsigned*       hist = (unsigned*)(ws + 20971520);                // 128 KB
        unsigned*       offs = (unsigned*)(ws + 21102592);                // 128 KB + 4
        unsigned*       curs = (unsigned*)(ws + 21233920);                // 128 KB
        unsigned short* Qw   = (unsigned short*)(ws + 21364992);          // 16 KB
        unsigned short* Pw   = (unsigned short*)(ws + 21381376);          // 16 KB
        unsigned short* Wu1p = (unsigned short*)(ws + 21397760);          // 32 KB
        unsigned short* Wu2p = (unsigned short*)(ws + 21430528);          // 16 KB

        hipMemsetAsync(hist, 0, 32768 * sizeof(unsigned), stream);
        pack_weights<<<32, 256, 0, stream>>>(Wm1, Qw, 64, 128);
        pack_weights<<<32, 256, 0, stream>>>(Wm1 + 64 * 128, Pw, 64, 128);
        pack_weights<<<64, 256, 0, stream>>>(Wu1, Wu1p, 128, 128);
        pack_weights<<<32, 256, 0, stream>>>(Wu2, Wu2p, 128, 64);
        precompute_pq<<<512, 256, 0, stream>>>(node_feats, Qw, Pw, Qp, Pp);
        hist_kernel<<<NEDGE / 256, 256, 0, stream>>>(eb, esrc, hist);
        scan_kernel<<<1, 1024, 0, stream>>>(hist, offs, curs);
        scatter_kernel<<<NEDGE / 256, 256, 0, stream>>>(eb, esrc, edst, evals, curs, pay);
        segment_kernel<<<32768 / 4, 256, 0, stream>>>(Qp, Pp, pay, offs, Wm2, bm1, bm2, out);
        node_kernel<0><<<(NB * NN) / 64, 256, 0, stream>>>(node_feats, out, nullptr,
                                                           Wu1p, bu1, Wu2p, bu2, out);
    } else {
        // ---- fallback: round-1 path (atomic scatter) ----
        float* counts          = (float*)ws;
        unsigned short* W1p    = (unsigned short*)(ws + 131072);
        unsigned short* W2p    = (unsigned short*)(ws + 163840);
        unsigned short* Wu1p   = (unsigned short*)(ws + 180224);
        unsigned short* Wu2p   = (unsigned short*)(ws + 212992);
        hipMemsetAsync(d_out, 0, (size_t)out_size * sizeof(float), stream);
        hipMemsetAsync(counts, 0, 32768 * sizeof(float), stream);
        pack_weights<<<64, 256, 0, stream>>>(Wm1, W1p, 128, 128);
        pack_weights<<<32, 256, 0, stream>>>(Wm2, W2p, 128, 64);
        pack_weights<<<64, 256, 0, stream>>>(Wu1, Wu1p, 128, 128);
        pack_weights<<<32, 256, 0, stream>>>(Wu2, Wu2p, 128, 64);
        edge_kernel<<<NEDGE / 64, 256, 0, stream>>>(node_feats, eb, esrc, edst, evals,
                                                    W1p, bm1, W2p, bm2, out, counts);
        node_kernel<1><<<(NB * NN) / 64, 256, 0, stream>>>(node_feats, out, counts,
                                                           Wu1p, bu1, Wu2p, bu2, out);
    }
}

// Round 3
// 194.237 us; speedup vs baseline: 2.1571x; 1.1918x over previous
//
#include <hip/hip_runtime.h>

#define NB 8
#define NN 4096
#define DNF 64
#define NEDGE 1048576
#define DM 64
#define FF 64

using f32x4 = __attribute__((ext_vector_type(4))) float;
using s16x8 = __attribute__((ext_vector_type(8))) short;

__device__ __forceinline__ unsigned short f2b(float f) {
    union { float f; unsigned u; } v; v.f = f;
    unsigned r = (v.u + 0x7fffu + ((v.u >> 16) & 1u)) >> 16;
    return (unsigned short)r;
}
__device__ __forceinline__ float b2f(unsigned short b) {
    union { unsigned u; float f; } v; v.u = ((unsigned)b) << 16;
    return v.f;
}
__device__ __forceinline__ float uif(unsigned u) {
    union { unsigned u; float f; } v; v.u = u;
    return v.f;
}

// Pack W [K x Ncols] (f32 row-major) into MFMA B-fragment order (bf16):
// out[((nt*KS + ks)*64 + lane)*8 + j] = W[(ks*32 + (lane>>4)*8 + j)*Ncols + nt*16 + (lane&15)]
__device__ __forceinline__ void pack_one(const float* __restrict__ W,
                                         unsigned short* __restrict__ out,
                                         int K, int Ncols, int idx) {
    int j = idx & 7;
    int lane = (idx >> 3) & 63;
    int frag = idx >> 9;
    int KS = K >> 5;
    int ks = frag % KS;
    int nt = frag / KS;
    int k = ks * 32 + ((lane >> 4) << 3) + j;
    int col = nt * 16 + (lane & 15);
    out[idx] = f2b(W[k * Ncols + col]);
}

__global__ void pack_all(const float* __restrict__ Wm1, const float* __restrict__ Wm2,
                         const float* __restrict__ Wu1, const float* __restrict__ Wu2,
                         unsigned short* __restrict__ Qw, unsigned short* __restrict__ Pw,
                         unsigned short* __restrict__ Wm2p,
                         unsigned short* __restrict__ Wu1p, unsigned short* __restrict__ Wu2p) {
    int idx = blockIdx.x * 256 + threadIdx.x;
    if (idx < 8192)        pack_one(Wm1,              Qw,   64, 128, idx);
    else if (idx < 16384)  pack_one(Wm1 + 64 * 128,   Pw,   64, 128, idx - 8192);
    else if (idx < 24576)  pack_one(Wm2,              Wm2p, 128, 64, idx - 16384);
    else if (idx < 40960)  pack_one(Wu1,              Wu1p, 128, 128, idx - 24576);
    else                   pack_one(Wu2,              Wu2p, 128, 64, idx - 40960);
}

__global__ void pack_weights(const float* __restrict__ W, unsigned short* __restrict__ out,
                             int K, int Ncols) {
    int idx = blockIdx.x * 256 + threadIdx.x;
    if (idx >= K * Ncols) return;
    pack_one(W, out, K, Ncols, idx);
}

// Q = X @ Wm1[0:64,:] + b1 (bias folded), P = X @ Wm1[64:128,:]  (32768 x 128, bf16)
__launch_bounds__(256, 4)
__global__ void precompute_pq(const float* __restrict__ X,
                              const unsigned short* __restrict__ Qw,
                              const unsigned short* __restrict__ Pw,
                              const float* __restrict__ b1,
                              unsigned short* __restrict__ Qp,
                              unsigned short* __restrict__ Pp) {
    __shared__ unsigned short A[64][72];
    const int tid = threadIdx.x;
    const int g0 = blockIdx.x * 64;
    for (int i = 0; i < 16; ++i) {
        int idx = i * 256 + tid;
        int node = idx >> 6;
        int f = idx & 63;
        A[node][f] = f2b(X[(size_t)(g0 + node) * DNF + f]);
    }
    __syncthreads();
    const int wave = tid >> 6, lane = tid & 63;
    const int lr = lane & 15, lq = lane >> 4;
    const int arow = wave * 16 + lr;
    s16x8 a[2];
#pragma unroll
    for (int ks = 0; ks < 2; ++ks)
        a[ks] = *reinterpret_cast<const s16x8*>(&A[arow][ks * 32 + lq * 8]);
#pragma unroll
    for (int nt = 0; nt < 8; ++nt) {
        f32x4 accQ = {0.f, 0.f, 0.f, 0.f};
        f32x4 accP = {0.f, 0.f, 0.f, 0.f};
#pragma unroll
        for (int ks = 0; ks < 2; ++ks) {
            s16x8 bq = *reinterpret_cast<const s16x8*>(&Qw[(((nt << 1) + ks) * 64 + lane) * 8]);
            s16x8 bp = *reinterpret_cast<const s16x8*>(&Pw[(((nt << 1) + ks) * 64 + lane) * 8]);
            accQ = __builtin_amdgcn_mfma_f32_16x16x32_bf16(a[ks], bq, accQ, 0, 0, 0);
            accP = __builtin_amdgcn_mfma_f32_16x16x32_bf16(a[ks], bp, accP, 0, 0, 0);
        }
        int col = nt * 16 + lr;
        float bias = b1[col];
#pragma unroll
        for (int j = 0; j < 4; ++j) {
            int row = g0 + wave * 16 + lq * 4 + j;
            Qp[(size_t)row * 128 + col] = f2b(accQ[j] + bias);
            Pp[(size_t)row * 128 + col] = f2b(accP[j]);
        }
    }
}

__global__ void hist_kernel(const int* __restrict__ eb, const int* __restrict__ esrc,
                            unsigned* __restrict__ hist) {
    int e = blockIdx.x * 256 + threadIdx.x;
    atomicAdd(&hist[eb[e] * NN + esrc[e]], 1u);
}

__launch_bounds__(1024)
__global__ void scan_kernel(const unsigned* __restrict__ hist,
                            unsigned* __restrict__ offs, unsigned* __restrict__ curs) {
    __shared__ unsigned part[1024];
    int t = threadIdx.x;
    unsigned v[32];
    unsigned s = 0;
#pragma unroll
    for (int i = 0; i < 32; ++i) { v[i] = hist[t * 32 + i]; s += v[i]; }
    part[t] = s;
    __syncthreads();
    for (int off = 1; off < 1024; off <<= 1) {
        unsigned x = (t >= off) ? part[t - off] : 0u;
        __syncthreads();
        part[t] += x;
        __syncthreads();
    }
    unsigned run = (t > 0) ? part[t - 1] : 0u;
#pragma unroll
    for (int i = 0; i < 32; ++i) {
        offs[t * 32 + i] = run;
        curs[t * 32 + i] = run;
        run += v[i];
    }
    if (t == 1023) offs[32768] = run;
}

// payload = dst (low16) | bf16(w) (high16)
__global__ void scatter_kernel(const int* __restrict__ eb, const int* __restrict__ esrc,
                               const int* __restrict__ edst, const float* __restrict__ evals,
                               unsigned* __restrict__ curs, unsigned* __restrict__ payload) {
    int e = blockIdx.x * 256 + threadIdx.x;
    int seg = eb[e] * NN + esrc[e];
    unsigned pos = atomicAdd(&curs[seg], 1u);
    payload[pos] = (unsigned)edst[e] | ((unsigned)f2b(evals[e]) << 16);
}

// 16 segments/block (4 waves x 4 serial). Per segment: s = sum_e w*relu(Q[src]+P[dst]+b1)
// (bias pre-folded into Q). Then one MFMA per wave: gathered = (S @ Wm2 + sumw*b2)/cnt.
__launch_bounds__(256, 8)
__global__ void segment_kernel(const unsigned short* __restrict__ Qp,
                               const unsigned short* __restrict__ Pp,
                               const unsigned* __restrict__ payload,
                               const unsigned* __restrict__ offs,
                               const unsigned short* __restrict__ Wm2p,
                               const float* __restrict__ b2,
                               float* __restrict__ gathered) {
    __shared__ unsigned short S[16][136];
    __shared__ float SW[16];   // sum of weights
    __shared__ float SC[16];   // 1/max(cnt,1)
    const int tid = threadIdx.x, wv = tid >> 6, lane = tid & 63;
    const int seg0 = blockIdx.x * 16;
    const unsigned* P32 = reinterpret_cast<const unsigned*>(Pp);
    const unsigned* Q32 = reinterpret_cast<const unsigned*>(Qp);

    for (int si = 0; si < 4; ++si) {
        const int row = wv * 4 + si;
        const int seg = seg0 + row;
        const unsigned start = offs[seg], end = offs[seg + 1];
        const int rowbase = (seg >> 12) << 12;   // b * NN
        unsigned qv = Q32[(size_t)seg * 64 + lane];
        float q0 = uif(qv << 16);
        float q1 = uif(qv & 0xffff0000u);
        float acc0 = 0.f, acc1 = 0.f, wsum = 0.f;

        for (unsigned base = start; base < end; base += 64) {
            unsigned pay = (base + (unsigned)lane < end) ? payload[base + lane] : 0u;
            wsum += uif(pay & 0xffff0000u);       // lane-parallel sumw (invalid lanes = 0)
            int m = (int)min(64u, end - base);
            for (int sub = 0; sub < m; sub += 8) {
                unsigned pv[8], wb[8];
#pragma unroll
                for (int k = 0; k < 8; ++k) {
                    unsigned c = (unsigned)__builtin_amdgcn_readlane((int)pay, sub + k);
                    wb[k] = c & 0xffff0000u;                     // scalar bf16 weight bits
                    int r = rowbase + (int)(c & 0xffffu);        // scalar P row
                    pv[k] = P32[(size_t)r * 64 + lane];
                }
#pragma unroll
                for (int k = 0; k < 8; ++k) {
                    float w = uif(wb[k]);
                    float p0 = uif(pv[k] << 16);
                    float p1 = uif(pv[k] & 0xffff0000u);
                    acc0 = fmaf(w, fmaxf(q0 + p0, 0.f), acc0);
                    acc1 = fmaf(w, fmaxf(q1 + p1, 0.f), acc1);
                }
            }
        }
        for (int m2 = 1; m2 < 64; m2 <<= 1) wsum += __shfl_xor(wsum, m2);
        unsigned sp = (unsigned)f2b(acc0) | ((unsigned)f2b(acc1) << 16);
        *reinterpret_cast<unsigned*>(&S[row][2 * lane]) = sp;
        if (lane == 0) {
            SW[row] = wsum;
            SC[row] = 1.0f / (float)max(end - start, 1u);
        }
    }
    __syncthreads();

    // MFMA: D[16 segs][16 dims] per wave (wv = col tile), K=128
    const int lr = lane & 15, lq = lane >> 4;
    s16x8 a[4];
#pragma unroll
    for (int ks = 0; ks < 4; ++ks)
        a[ks] = *reinterpret_cast<const s16x8*>(&S[lr][ks * 32 + lq * 8]);
    f32x4 acc = {0.f, 0.f, 0.f, 0.f};
#pragma unroll
    for (int ks = 0; ks < 4; ++ks) {
        s16x8 bf = *reinterpret_cast<const s16x8*>(&Wm2p[(((wv << 2) + ks) * 64 + lane) * 8]);
        acc = __builtin_amdgcn_mfma_f32_16x16x32_bf16(a[ks], bf, acc, 0, 0, 0);
    }
    float bb = b2[wv * 16 + lr];
#pragma unroll
    for (int j = 0; j < 4; ++j) {
        int r = lq * 4 + j;
        gathered[(size_t)(seg0 + r) * 64 + wv * 16 + lr] = (acc[j] + SW[r] * bb) * SC[r];
    }
}

// ---------------- node update (unchanged) + fallback kernels ----------------

template<int SCALE>
__launch_bounds__(256, 4)
__global__ void node_kernel(const float* __restrict__ node_feats,
                            const float* __restrict__ sums, const float* __restrict__ counts,
                            const unsigned short* __restrict__ W1p, const float* __restrict__ b1,
                            const unsigned short* __restrict__ W2p, const float* __restrict__ b2,
                            float* __restrict__ out) {
    __shared__ unsigned short A1[64][136];
    __shared__ unsigned short Hs[64][136];
    const int tid = threadIdx.x;
    const int g0 = blockIdx.x * 64;
    for (int i = 0; i < 16; ++i) {
        int idx = i * 256 + tid;
        int node = idx >> 6;
        int p = idx & 63;
        int g = g0 + node;
        float2 v;
        if (p < 32) {
            v = *reinterpret_cast<const float2*>(node_feats + (size_t)g * DNF + 2 * p);
        } else {
            float2 s = *reinterpret_cast<const float2*>(sums + (size_t)g * DM + 2 * p - 64);
            if (SCALE) {
                float scale = 1.0f / fmaxf(counts[g], 1.0f);
                s.x *= scale; s.y *= scale;
            }
            v = s;
        }
        unsigned packed = (unsigned)f2b(v.x) | ((unsigned)f2b(v.y) << 16);
        *reinterpret_cast<unsigned*>(&A1[node][2 * p]) = packed;
    }
    __syncthreads();
    const int wave = tid >> 6, lane = tid & 63;
    const int lr = lane & 15, lq = lane >> 4;
    const int arow = wave * 16 + lr;
    s16x8 a[4];
#pragma unroll
    for (int ks = 0; ks < 4; ++ks)
        a[ks] = *reinterpret_cast<const s16x8*>(&A1[arow][ks * 32 + lq * 8]);
#pragma unroll
    for (int nt = 0; nt < 8; ++nt) {
        f32x4 acc = {0.f, 0.f, 0.f, 0.f};
#pragma unroll
        for (int ks = 0; ks < 4; ++ks) {
            s16x8 bf = *reinterpret_cast<const s16x8*>(&W1p[(((nt << 2) + ks) * 64 + lane) * 8]);
            acc = __builtin_amdgcn_mfma_f32_16x16x32_bf16(a[ks], bf, acc, 0, 0, 0);
        }
        float bias = b1[nt * 16 + lr];
#pragma unroll
        for (int j = 0; j < 4; ++j) {
            float h = acc[j] + bias;
            h = h > 0.f ? h : 0.f;
            Hs[wave * 16 + lq * 4 + j][nt * 16 + lr] = f2b(h);
        }
    }
    s16x8 a2[4];
#pragma unroll
    for (int ks = 0; ks < 4; ++ks)
        a2[ks] = *reinterpret_cast<const s16x8*>(&Hs[arow][ks * 32 + lq * 8]);
#pragma unroll
    for (int nt = 0; nt < 4; ++nt) {
        f32x4 acc = {0.f, 0.f, 0.f, 0.f};
#pragma unroll
        for (int ks = 0; ks < 4; ++ks) {
            s16x8 bf = *reinterpret_cast<const s16x8*>(&W2p[(((nt << 2) + ks) * 64 + lane) * 8]);
            acc = __builtin_amdgcn_mfma_f32_16x16x32_bf16(a2[ks], bf, acc, 0, 0, 0);
        }
        float bias = b2[nt * 16 + lr];
#pragma unroll
        for (int j = 0; j < 4; ++j) {
            int g = g0 + wave * 16 + lq * 4 + j;
            out[(size_t)g * FF + nt * 16 + lr] = acc[j] + bias;
        }
    }
}

__launch_bounds__(256, 4)
__global__ void edge_kernel(const float* __restrict__ node_feats,
                            const int* __restrict__ eb, const int* __restrict__ esrc,
                            const int* __restrict__ edst, const float* __restrict__ evals,
                            const unsigned short* __restrict__ W1p, const float* __restrict__ b1,
                            const unsigned short* __restrict__ W2p, const float* __restrict__ b2,
                            float* __restrict__ sums, float* __restrict__ counts) {
    __shared__ unsigned short A1[64][136];
    __shared__ unsigned short Hs[64][136];
    const int tid = threadIdx.x;
    const int e0 = blockIdx.x * 64;
    if (tid < 64) {
        int e = e0 + tid;
        atomicAdd(&counts[eb[e] * NN + esrc[e]], 1.0f);
    }
    for (int i = 0; i < 16; ++i) {
        int idx = i * 256 + tid;
        int edge = idx >> 6;
        int p = idx & 63;
        int e = e0 + edge;
        int b = eb[e];
        const float* row;
        if (p < 32) row = node_feats + ((size_t)b * NN + esrc[e]) * DNF;
        else        row = node_feats + ((size_t)b * NN + edst[e]) * DNF - 64;
        float2 v = *reinterpret_cast<const float2*>(row + 2 * p);
        unsigned packed = (unsigned)f2b(v.x) | ((unsigned)f2b(v.y) << 16);
        *reinterpret_cast<unsigned*>(&A1[edge][2 * p]) = packed;
    }
    __syncthreads();
    const int wave = tid >> 6, lane = tid & 63;
    const int lr = lane & 15, lq = lane >> 4;
    const int arow = wave * 16 + lr;
    s16x8 a[4];
#pragma unroll
    for (int ks = 0; ks < 4; ++ks)
        a[ks] = *reinterpret_cast<const s16x8*>(&A1[arow][ks * 32 + lq * 8]);
#pragma unroll
    for (int nt = 0; nt < 8; ++nt) {
        f32x4 acc = {0.f, 0.f, 0.f, 0.f};
#pragma unroll
        for (int ks = 0; ks < 4; ++ks) {
            s16x8 bf = *reinterpret_cast<const s16x8*>(&W1p[(((nt << 2) + ks) * 64 + lane) * 8]);
            acc = __builtin_amdgcn_mfma_f32_16x16x32_bf16(a[ks], bf, acc, 0, 0, 0);
        }
        float bias = b1[nt * 16 + lr];
#pragma unroll
        for (int j = 0; j < 4; ++j) {
            float h = acc[j] + bias;
            h = h > 0.f ? h : 0.f;
            Hs[wave * 16 + lq * 4 + j][nt * 16 + lr] = f2b(h);
        }
    }
    s16x8 a2[4];
#pragma unroll
    for (int ks = 0; ks < 4; ++ks)
        a2[ks] = *reinterpret_cast<const s16x8*>(&Hs[arow][ks * 32 + lq * 8]);
    float ev[4]; int seg4[4];
#pragma unroll
    for (int j = 0; j < 4; ++j) {
        int r = e0 + wave * 16 + lq * 4 + j;
        ev[j] = evals[r];
        seg4[j] = eb[r] * NN + esrc[r];
    }
#pragma unroll
    for (int nt = 0; nt < 4; ++nt) {
        f32x4 acc = {0.f, 0.f, 0.f, 0.f};
#pragma unroll
        for (int ks = 0; ks < 4; ++ks) {
            s16x8 bf = *reinterpret_cast<const s16x8*>(&W2p[(((nt << 2) + ks) * 64 + lane) * 8]);
            acc = __builtin_amdgcn_mfma_f32_16x16x32_bf16(a2[ks], bf, acc, 0, 0, 0);
        }
        float bias = b2[nt * 16 + lr];
#pragma unroll
        for (int j = 0; j < 4; ++j) {
            float m = (acc[j] + bias) * ev[j];
            atomicAdd(&sums[(size_t)seg4[j] * DM + nt * 16 + lr], m);
        }
    }
}

extern "C" void kernel_launch(void* const* d_in, const int* in_sizes, int n_in,
                              void* d_out, int out_size, void* d_ws, size_t ws_size,
                              hipStream_t stream) {
    const float* node_feats = (const float*)d_in[0];
    const int*   eb    = (const int*)d_in[1];
    const int*   esrc  = (const int*)d_in[2];
    const int*   edst  = (const int*)d_in[3];
    const float* evals = (const float*)d_in[4];
    const float* Wm1 = (const float*)d_in[5];
    const float* bm1 = (const float*)d_in[6];
    const float* Wm2 = (const float*)d_in[7];
    const float* bm2 = (const float*)d_in[8];
    const float* Wu1 = (const float*)d_in[9];
    const float* bu1 = (const float*)d_in[10];
    const float* Wu2 = (const float*)d_in[11];
    const float* bu2 = (const float*)d_in[12];
    float* out = (float*)d_out;
    char* ws = (char*)d_ws;

    const size_t NEED = 22u * 1024 * 1024;
    if (ws_size >= NEED) {
        unsigned short* Qp   = (unsigned short*)(ws);                     // 8 MB
        unsigned short* Pp   = (unsigned short*)(ws + 8388608);           // 8 MB
        unsigned*       pay  = (unsigned*)(ws + 16777216);                // 4 MB
        unsigned*       hist = (unsigned*)(ws + 20971520);                // 128 KB
        unsigned*       offs = (unsigned*)(ws + 21102592);                // 128 KB + 4
        unsigned*       curs = (unsigned*)(ws + 21233920);                // 128 KB
        unsigned short* Qw   = (unsigned short*)(ws + 21364992);          // 16 KB
        unsigned short* Pw   = (unsigned short*)(ws + 21381376);          // 16 KB
        unsigned short* Wu1p = (unsigned short*)(ws + 21397760);          // 32 KB
        unsigned short* Wu2p = (unsigned short*)(ws + 21430528);          // 16 KB
        unsigned short* Wm2p = (unsigned short*)(ws + 21446912);          // 16 KB

        hipMemsetAsync(hist, 0, 32768 * sizeof(unsigned), stream);
        pack_all<<<192, 256, 0, stream>>>(Wm1, Wm2, Wu1, Wu2, Qw, Pw, Wm2p, Wu1p, Wu2p);
        precompute_pq<<<512, 256, 0, stream>>>(node_feats, Qw, Pw, bm1, Qp, Pp);
        hist_kernel<<<NEDGE / 256, 256, 0, stream>>>(eb, esrc, hist);
        scan_kernel<<<1, 1024, 0, stream>>>(hist, offs, curs);
        scatter_kernel<<<NEDGE / 256, 256, 0, stream>>>(eb, esrc, edst, evals, curs, pay);
        segment_kernel<<<32768 / 16, 256, 0, stream>>>(Qp, Pp, pay, offs, Wm2p, bm2, out);
        node_kernel<0><<<(NB * NN) / 64, 256, 0, stream>>>(node_feats, out, nullptr,
                                                           Wu1p, bu1, Wu2p, bu2, out);
    } else {
        float* counts          = (float*)ws;
        unsigned short* W1p    = (unsigned short*)(ws + 131072);
        unsigned short* W2p    = (unsigned short*)(ws + 163840);
        unsigned short* Wu1p   = (unsigned short*)(ws + 180224);
        unsigned short* Wu2p   = (unsigned short*)(ws + 212992);
        hipMemsetAsync(d_out, 0, (size_t)out_size * sizeof(float), stream);
        hipMemsetAsync(counts, 0, 32768 * sizeof(float), stream);
        pack_weights<<<64, 256, 0, stream>>>(Wm1, W1p, 128, 128);
        pack_weights<<<32, 256, 0, stream>>>(Wm2, W2p, 128, 64);
        pack_weights<<<64, 256, 0, stream>>>(Wu1, Wu1p, 128, 128);
        pack_weights<<<32, 256, 0, stream>>>(Wu2, Wu2p, 128, 64);
        edge_kernel<<<NEDGE / 64, 256, 0, stream>>>(node_feats, eb, esrc, edst, evals,
                                                    W1p, bm1, W2p, bm2, out, counts);
        node_kernel<1><<<(NB * NN) / 64, 256, 0, stream>>>(node_feats, out, counts,
                                                           Wu1p, bu1, Wu2p, bu2, out);
    }
}

// Round 4
// 140.252 us; speedup vs baseline: 2.9874x; 1.3849x over previous
//
#include <hip/hip_runtime.h>

#define NB 8
#define NN 4096
#define DNF 64
#define NEDGE 1048576
#define DM 64
#define FF 64
#define SLOTS 96
#define OVFCAP 65536

using f32x4 = __attribute__((ext_vector_type(4))) float;
using s16x8 = __attribute__((ext_vector_type(8))) short;

__device__ __forceinline__ unsigned short f2b(float f) {
    union { float f; unsigned u; } v; v.f = f;
    unsigned r = (v.u + 0x7fffu + ((v.u >> 16) & 1u)) >> 16;
    return (unsigned short)r;
}
__device__ __forceinline__ float b2f(unsigned short b) {
    union { unsigned u; float f; } v; v.u = ((unsigned)b) << 16;
    return v.f;
}
__device__ __forceinline__ float uif(unsigned u) {
    union { unsigned u; float f; } v; v.u = u;
    return v.f;
}

// Pack W [K x Ncols] (f32 row-major) into MFMA B-fragment order (bf16)
__device__ __forceinline__ void pack_one(const float* __restrict__ W,
                                         unsigned short* __restrict__ out,
                                         int K, int Ncols, int idx) {
    int j = idx & 7;
    int lane = (idx >> 3) & 63;
    int frag = idx >> 9;
    int KS = K >> 5;
    int ks = frag % KS;
    int nt = frag / KS;
    int k = ks * 32 + ((lane >> 4) << 3) + j;
    int col = nt * 16 + (lane & 15);
    out[idx] = f2b(W[k * Ncols + col]);
}

__global__ void pack_all(const float* __restrict__ Wm1, const float* __restrict__ Wm2,
                         const float* __restrict__ Wu1, const float* __restrict__ Wu2,
                         unsigned short* __restrict__ Qw, unsigned short* __restrict__ Pw,
                         unsigned short* __restrict__ Wm2p,
                         unsigned short* __restrict__ Wu1p, unsigned short* __restrict__ Wu2p) {
    int idx = blockIdx.x * 256 + threadIdx.x;
    if (idx < 8192)        pack_one(Wm1,              Qw,   64, 128, idx);
    else if (idx < 16384)  pack_one(Wm1 + 64 * 128,   Pw,   64, 128, idx - 8192);
    else if (idx < 24576)  pack_one(Wm2,              Wm2p, 128, 64, idx - 16384);
    else if (idx < 40960)  pack_one(Wu1,              Wu1p, 128, 128, idx - 24576);
    else                   pack_one(Wu2,              Wu2p, 128, 64, idx - 40960);
}

__global__ void pack_weights(const float* __restrict__ W, unsigned short* __restrict__ out,
                             int K, int Ncols) {
    int idx = blockIdx.x * 256 + threadIdx.x;
    if (idx >= K * Ncols) return;
    pack_one(W, out, K, Ncols, idx);
}

// Q = X @ Wm1[0:64,:] + b1 (bias folded), P = X @ Wm1[64:128,:]
__launch_bounds__(256, 4)
__global__ void precompute_pq(const float* __restrict__ X,
                              const unsigned short* __restrict__ Qw,
                              const unsigned short* __restrict__ Pw,
                              const float* __restrict__ b1,
                              unsigned short* __restrict__ Qp,
                              unsigned short* __restrict__ Pp) {
    __shared__ unsigned short A[64][72];
    const int tid = threadIdx.x;
    const int g0 = blockIdx.x * 64;
    for (int i = 0; i < 16; ++i) {
        int idx = i * 256 + tid;
        int node = idx >> 6;
        int f = idx & 63;
        A[node][f] = f2b(X[(size_t)(g0 + node) * DNF + f]);
    }
    __syncthreads();
    const int wave = tid >> 6, lane = tid & 63;
    const int lr = lane & 15, lq = lane >> 4;
    const int arow = wave * 16 + lr;
    s16x8 a[2];
#pragma unroll
    for (int ks = 0; ks < 2; ++ks)
        a[ks] = *reinterpret_cast<const s16x8*>(&A[arow][ks * 32 + lq * 8]);
#pragma unroll
    for (int nt = 0; nt < 8; ++nt) {
        f32x4 accQ = {0.f, 0.f, 0.f, 0.f};
        f32x4 accP = {0.f, 0.f, 0.f, 0.f};
#pragma unroll
        for (int ks = 0; ks < 2; ++ks) {
            s16x8 bq = *reinterpret_cast<const s16x8*>(&Qw[(((nt << 1) + ks) * 64 + lane) * 8]);
            s16x8 bp = *reinterpret_cast<const s16x8*>(&Pw[(((nt << 1) + ks) * 64 + lane) * 8]);
            accQ = __builtin_amdgcn_mfma_f32_16x16x32_bf16(a[ks], bq, accQ, 0, 0, 0);
            accP = __builtin_amdgcn_mfma_f32_16x16x32_bf16(a[ks], bp, accP, 0, 0, 0);
        }
        int col = nt * 16 + lr;
        float bias = b1[col];
#pragma unroll
        for (int j = 0; j < 4; ++j) {
            int row = g0 + wave * 16 + lq * 4 + j;
            Qp[(size_t)row * 128 + col] = f2b(accQ[j] + bias);
            Pp[(size_t)row * 128 + col] = f2b(accP[j]);
        }
    }
}

// Slot scatter: 8 edges/thread ILP; pos = atomicAdd; payload = dst | bf16(w)<<16.
__launch_bounds__(256, 8)
__global__ void scatter_slots(const int* __restrict__ eb, const int* __restrict__ esrc,
                              const int* __restrict__ edst, const float* __restrict__ evals,
                              unsigned* __restrict__ curs, unsigned* __restrict__ payslot,
                              unsigned* __restrict__ ovf_cnt, unsigned* __restrict__ ovf_seg,
                              unsigned* __restrict__ ovf_pay) {
    const int t0 = blockIdx.x * 2048 + threadIdx.x;
    int seg[8]; unsigned pk[8];
#pragma unroll
    for (int k = 0; k < 8; ++k) {
        int e = t0 + k * 256;
        seg[k] = eb[e] * NN + esrc[e];
        pk[k] = (unsigned)edst[e] | ((unsigned)f2b(evals[e]) << 16);
    }
    unsigned pos[8];
#pragma unroll
    for (int k = 0; k < 8; ++k) pos[k] = atomicAdd(&curs[seg[k]], 1u);
#pragma unroll
    for (int k = 0; k < 8; ++k) {
        if (pos[k] < (unsigned)SLOTS) {
            payslot[(size_t)seg[k] * SLOTS + pos[k]] = pk[k];
        } else {
            unsigned o = atomicAdd(ovf_cnt, 1u);
            if (o < (unsigned)OVFCAP) { ovf_seg[o] = (unsigned)seg[k]; ovf_pay[o] = pk[k]; }
        }
    }
}

// 16 segments/block (4 waves x 4 serial); reads slotted payload; MFMA tail for Wm2.
__launch_bounds__(256, 8)
__global__ void segment_slots(const unsigned short* __restrict__ Qp,
                              const unsigned short* __restrict__ Pp,
                              const unsigned* __restrict__ payslot,
                              const unsigned* __restrict__ curs,
                              const unsigned* __restrict__ ovf_cnt,
                              const unsigned* __restrict__ ovf_seg,
                              const unsigned* __restrict__ ovf_pay,
                              const unsigned short* __restrict__ Wm2p,
                              const float* __restrict__ b2,
                              float* __restrict__ gathered) {
    __shared__ unsigned short S[16][136];
    __shared__ float SW[16];
    __shared__ float SC[16];
    const int tid = threadIdx.x, wv = tid >> 6, lane = tid & 63;
    const int seg0 = blockIdx.x * 16;
    const unsigned* P32 = reinterpret_cast<const unsigned*>(Pp);
    const unsigned* Q32 = reinterpret_cast<const unsigned*>(Qp);
    const unsigned novf = ovf_cnt[0];

    for (int si = 0; si < 4; ++si) {
        const int row = wv * 4 + si;
        const int seg = seg0 + row;
        const unsigned cnt = curs[seg];
        const unsigned cl = min(cnt, (unsigned)SLOTS);
        const int rowbase = (seg >> 12) << 12;   // b * NN
        unsigned qv = Q32[(size_t)seg * 64 + lane];
        float q0 = uif(qv << 16);
        float q1 = uif(qv & 0xffff0000u);
        float acc0 = 0.f, acc1 = 0.f, wsum = 0.f;

        for (unsigned base = 0; base < cl; base += 64) {
            unsigned idx = base + (unsigned)lane;
            unsigned pay = (idx < cl) ? payslot[(size_t)seg * SLOTS + idx] : 0u;
            wsum += uif(pay & 0xffff0000u);
            int m = (int)min(64u, cl - base);
            for (int sub = 0; sub < m; sub += 8) {
                unsigned pv[8], wb[8];
#pragma unroll
                for (int k = 0; k < 8; ++k) {
                    unsigned c = (unsigned)__builtin_amdgcn_readlane((int)pay, sub + k);
                    wb[k] = c & 0xffff0000u;
                    int r = rowbase + (int)(c & 0xffffu);
                    pv[k] = P32[(size_t)r * 64 + lane];
                }
#pragma unroll
                for (int k = 0; k < 8; ++k) {
                    float w = uif(wb[k]);
                    float p0 = uif(pv[k] << 16);
                    float p1 = uif(pv[k] & 0xffff0000u);
                    acc0 = fmaf(w, fmaxf(q0 + p0, 0.f), acc0);
                    acc1 = fmaf(w, fmaxf(q1 + p1, 0.f), acc1);
                }
            }
        }
        for (int m2 = 1; m2 < 64; m2 <<= 1) wsum += __shfl_xor(wsum, m2);
        // overflow path (normally novf == 0): wave-uniform scan
        if (novf > 0) {
            unsigned ncl = min(novf, (unsigned)OVFCAP);
            for (unsigned i = 0; i < ncl; ++i) {
                if (ovf_seg[i] == (unsigned)seg) {
                    unsigned c = ovf_pay[i];
                    float w = uif(c & 0xffff0000u);
                    unsigned pv = P32[(size_t)(rowbase + (int)(c & 0xffffu)) * 64 + lane];
                    acc0 = fmaf(w, fmaxf(q0 + uif(pv << 16), 0.f), acc0);
                    acc1 = fmaf(w, fmaxf(q1 + uif(pv & 0xffff0000u), 0.f), acc1);
                    wsum += w;
                }
            }
        }
        unsigned sp = (unsigned)f2b(acc0) | ((unsigned)f2b(acc1) << 16);
        *reinterpret_cast<unsigned*>(&S[row][2 * lane]) = sp;
        if (lane == 0) {
            SW[row] = wsum;
            SC[row] = 1.0f / (float)max(cnt, 1u);
        }
    }
    __syncthreads();

    const int lr = lane & 15, lq = lane >> 4;
    s16x8 a[4];
#pragma unroll
    for (int ks = 0; ks < 4; ++ks)
        a[ks] = *reinterpret_cast<const s16x8*>(&S[lr][ks * 32 + lq * 8]);
    f32x4 acc = {0.f, 0.f, 0.f, 0.f};
#pragma unroll
    for (int ks = 0; ks < 4; ++ks) {
        s16x8 bf = *reinterpret_cast<const s16x8*>(&Wm2p[(((wv << 2) + ks) * 64 + lane) * 8]);
        acc = __builtin_amdgcn_mfma_f32_16x16x32_bf16(a[ks], bf, acc, 0, 0, 0);
    }
    float bb = b2[wv * 16 + lr];
#pragma unroll
    for (int j = 0; j < 4; ++j) {
        int r = lq * 4 + j;
        gathered[(size_t)(seg0 + r) * 64 + wv * 16 + lr] = (acc[j] + SW[r] * bb) * SC[r];
    }
}

// ---------------- middle-path (round 3) kernels ----------------

__global__ void hist_kernel(const int* __restrict__ eb, const int* __restrict__ esrc,
                            unsigned* __restrict__ hist) {
    int e = blockIdx.x * 256 + threadIdx.x;
    atomicAdd(&hist[eb[e] * NN + esrc[e]], 1u);
}

__launch_bounds__(1024)
__global__ void scan_kernel(const unsigned* __restrict__ hist,
                            unsigned* __restrict__ offs, unsigned* __restrict__ curs) {
    __shared__ unsigned part[1024];
    int t = threadIdx.x;
    unsigned v[32];
    unsigned s = 0;
#pragma unroll
    for (int i = 0; i < 32; ++i) { v[i] = hist[t * 32 + i]; s += v[i]; }
    part[t] = s;
    __syncthreads();
    for (int off = 1; off < 1024; off <<= 1) {
        unsigned x = (t >= off) ? part[t - off] : 0u;
        __syncthreads();
        part[t] += x;
        __syncthreads();
    }
    unsigned run = (t > 0) ? part[t - 1] : 0u;
#pragma unroll
    for (int i = 0; i < 32; ++i) {
        offs[t * 32 + i] = run;
        curs[t * 32 + i] = run;
        run += v[i];
    }
    if (t == 1023) offs[32768] = run;
}

__global__ void scatter_kernel(const int* __restrict__ eb, const int* __restrict__ esrc,
                               const int* __restrict__ edst, const float* __restrict__ evals,
                               unsigned* __restrict__ curs, unsigned* __restrict__ payload) {
    int e = blockIdx.x * 256 + threadIdx.x;
    int seg = eb[e] * NN + esrc[e];
    unsigned pos = atomicAdd(&curs[seg], 1u);
    payload[pos] = (unsigned)edst[e] | ((unsigned)f2b(evals[e]) << 16);
}

__launch_bounds__(256, 8)
__global__ void segment_kernel(const unsigned short* __restrict__ Qp,
                               const unsigned short* __restrict__ Pp,
                               const unsigned* __restrict__ payload,
                               const unsigned* __restrict__ offs,
                               const unsigned short* __restrict__ Wm2p,
                               const float* __restrict__ b2,
                               float* __restrict__ gathered) {
    __shared__ unsigned short S[16][136];
    __shared__ float SW[16];
    __shared__ float SC[16];
    const int tid = threadIdx.x, wv = tid >> 6, lane = tid & 63;
    const int seg0 = blockIdx.x * 16;
    const unsigned* P32 = reinterpret_cast<const unsigned*>(Pp);
    const unsigned* Q32 = reinterpret_cast<const unsigned*>(Qp);

    for (int si = 0; si < 4; ++si) {
        const int row = wv * 4 + si;
        const int seg = seg0 + row;
        const unsigned start = offs[seg], end = offs[seg + 1];
        const int rowbase = (seg >> 12) << 12;
        unsigned qv = Q32[(size_t)seg * 64 + lane];
        float q0 = uif(qv << 16);
        float q1 = uif(qv & 0xffff0000u);
        float acc0 = 0.f, acc1 = 0.f, wsum = 0.f;

        for (unsigned base = start; base < end; base += 64) {
            unsigned pay = (base + (unsigned)lane < end) ? payload[base + lane] : 0u;
            wsum += uif(pay & 0xffff0000u);
            int m = (int)min(64u, end - base);
            for (int sub = 0; sub < m; sub += 8) {
                unsigned pv[8], wb[8];
#pragma unroll
                for (int k = 0; k < 8; ++k) {
                    unsigned c = (unsigned)__builtin_amdgcn_readlane((int)pay, sub + k);
                    wb[k] = c & 0xffff0000u;
                    int r = rowbase + (int)(c & 0xffffu);
                    pv[k] = P32[(size_t)r * 64 + lane];
                }
#pragma unroll
                for (int k = 0; k < 8; ++k) {
                    float w = uif(wb[k]);
                    float p0 = uif(pv[k] << 16);
                    float p1 = uif(pv[k] & 0xffff0000u);
                    acc0 = fmaf(w, fmaxf(q0 + p0, 0.f), acc0);
                    acc1 = fmaf(w, fmaxf(q1 + p1, 0.f), acc1);
                }
            }
        }
        for (int m2 = 1; m2 < 64; m2 <<= 1) wsum += __shfl_xor(wsum, m2);
        unsigned sp = (unsigned)f2b(acc0) | ((unsigned)f2b(acc1) << 16);
        *reinterpret_cast<unsigned*>(&S[row][2 * lane]) = sp;
        if (lane == 0) {
            SW[row] = wsum;
            SC[row] = 1.0f / (float)max(end - start, 1u);
        }
    }
    __syncthreads();

    const int lr = lane & 15, lq = lane >> 4;
    s16x8 a[4];
#pragma unroll
    for (int ks = 0; ks < 4; ++ks)
        a[ks] = *reinterpret_cast<const s16x8*>(&S[lr][ks * 32 + lq * 8]);
    f32x4 acc = {0.f, 0.f, 0.f, 0.f};
#pragma unroll
    for (int ks = 0; ks < 4; ++ks) {
        s16x8 bf = *reinterpret_cast<const s16x8*>(&Wm2p[(((wv << 2) + ks) * 64 + lane) * 8]);
        acc = __builtin_amdgcn_mfma_f32_16x16x32_bf16(a[ks], bf, acc, 0, 0, 0);
    }
    float bb = b2[wv * 16 + lr];
#pragma unroll
    for (int j = 0; j < 4; ++j) {
        int r = lq * 4 + j;
        gathered[(size_t)(seg0 + r) * 64 + wv * 16 + lr] = (acc[j] + SW[r] * bb) * SC[r];
    }
}

// ---------------- node update + legacy fallback ----------------

template<int SCALE>
__launch_bounds__(256, 4)
__global__ void node_kernel(const float* __restrict__ node_feats,
                            const float* __restrict__ sums, const float* __restrict__ counts,
                            const unsigned short* __restrict__ W1p, const float* __restrict__ b1,
                            const unsigned short* __restrict__ W2p, const float* __restrict__ b2,
                            float* __restrict__ out) {
    __shared__ unsigned short A1[64][136];
    __shared__ unsigned short Hs[64][136];
    const int tid = threadIdx.x;
    const int g0 = blockIdx.x * 64;
    for (int i = 0; i < 16; ++i) {
        int idx = i * 256 + tid;
        int node = idx >> 6;
        int p = idx & 63;
        int g = g0 + node;
        float2 v;
        if (p < 32) {
            v = *reinterpret_cast<const float2*>(node_feats + (size_t)g * DNF + 2 * p);
        } else {
            float2 s = *reinterpret_cast<const float2*>(sums + (size_t)g * DM + 2 * p - 64);
            if (SCALE) {
                float scale = 1.0f / fmaxf(counts[g], 1.0f);
                s.x *= scale; s.y *= scale;
            }
            v = s;
        }
        unsigned packed = (unsigned)f2b(v.x) | ((unsigned)f2b(v.y) << 16);
        *reinterpret_cast<unsigned*>(&A1[node][2 * p]) = packed;
    }
    __syncthreads();
    const int wave = tid >> 6, lane = tid & 63;
    const int lr = lane & 15, lq = lane >> 4;
    const int arow = wave * 16 + lr;
    s16x8 a[4];
#pragma unroll
    for (int ks = 0; ks < 4; ++ks)
        a[ks] = *reinterpret_cast<const s16x8*>(&A1[arow][ks * 32 + lq * 8]);
#pragma unroll
    for (int nt = 0; nt < 8; ++nt) {
        f32x4 acc = {0.f, 0.f, 0.f, 0.f};
#pragma unroll
        for (int ks = 0; ks < 4; ++ks) {
            s16x8 bf = *reinterpret_cast<const s16x8*>(&W1p[(((nt << 2) + ks) * 64 + lane) * 8]);
            acc = __builtin_amdgcn_mfma_f32_16x16x32_bf16(a[ks], bf, acc, 0, 0, 0);
        }
        float bias = b1[nt * 16 + lr];
#pragma unroll
        for (int j = 0; j < 4; ++j) {
            float h = acc[j] + bias;
            h = h > 0.f ? h : 0.f;
            Hs[wave * 16 + lq * 4 + j][nt * 16 + lr] = f2b(h);
        }
    }
    s16x8 a2[4];
#pragma unroll
    for (int ks = 0; ks < 4; ++ks)
        a2[ks] = *reinterpret_cast<const s16x8*>(&Hs[arow][ks * 32 + lq * 8]);
#pragma unroll
    for (int nt = 0; nt < 4; ++nt) {
        f32x4 acc = {0.f, 0.f, 0.f, 0.f};
#pragma unroll
        for (int ks = 0; ks < 4; ++ks) {
            s16x8 bf = *reinterpret_cast<const s16x8*>(&W2p[(((nt << 2) + ks) * 64 + lane) * 8]);
            acc = __builtin_amdgcn_mfma_f32_16x16x32_bf16(a2[ks], bf, acc, 0, 0, 0);
        }
        float bias = b2[nt * 16 + lr];
#pragma unroll
        for (int j = 0; j < 4; ++j) {
            int g = g0 + wave * 16 + lq * 4 + j;
            out[(size_t)g * FF + nt * 16 + lr] = acc[j] + bias;
        }
    }
}

__launch_bounds__(256, 4)
__global__ void edge_kernel(const float* __restrict__ node_feats,
                            const int* __restrict__ eb, const int* __restrict__ esrc,
                            const int* __restrict__ edst, const float* __restrict__ evals,
                            const unsigned short* __restrict__ W1p, const float* __restrict__ b1,
                            const unsigned short* __restrict__ W2p, const float* __restrict__ b2,
                            float* __restrict__ sums, float* __restrict__ counts) {
    __shared__ unsigned short A1[64][136];
    __shared__ unsigned short Hs[64][136];
    const int tid = threadIdx.x;
    const int e0 = blockIdx.x * 64;
    if (tid < 64) {
        int e = e0 + tid;
        atomicAdd(&counts[eb[e] * NN + esrc[e]], 1.0f);
    }
    for (int i = 0; i < 16; ++i) {
        int idx = i * 256 + tid;
        int edge = idx >> 6;
        int p = idx & 63;
        int e = e0 + edge;
        int b = eb[e];
        const float* row;
        if (p < 32) row = node_feats + ((size_t)b * NN + esrc[e]) * DNF;
        else        row = node_feats + ((size_t)b * NN + edst[e]) * DNF - 64;
        float2 v = *reinterpret_cast<const float2*>(row + 2 * p);
        unsigned packed = (unsigned)f2b(v.x) | ((unsigned)f2b(v.y) << 16);
        *reinterpret_cast<unsigned*>(&A1[edge][2 * p]) = packed;
    }
    __syncthreads();
    const int wave = tid >> 6, lane = tid & 63;
    const int lr = lane & 15, lq = lane >> 4;
    const int arow = wave * 16 + lr;
    s16x8 a[4];
#pragma unroll
    for (int ks = 0; ks < 4; ++ks)
        a[ks] = *reinterpret_cast<const s16x8*>(&A1[arow][ks * 32 + lq * 8]);
#pragma unroll
    for (int nt = 0; nt < 8; ++nt) {
        f32x4 acc = {0.f, 0.f, 0.f, 0.f};
#pragma unroll
        for (int ks = 0; ks < 4; ++ks) {
            s16x8 bf = *reinterpret_cast<const s16x8*>(&W1p[(((nt << 2) + ks) * 64 + lane) * 8]);
            acc = __builtin_amdgcn_mfma_f32_16x16x32_bf16(a[ks], bf, acc, 0, 0, 0);
        }
        float bias = b1[nt * 16 + lr];
#pragma unroll
        for (int j = 0; j < 4; ++j) {
            float h = acc[j] + bias;
            h = h > 0.f ? h : 0.f;
            Hs[wave * 16 + lq * 4 + j][nt * 16 + lr] = f2b(h);
        }
    }
    s16x8 a2[4];
#pragma unroll
    for (int ks = 0; ks < 4; ++ks)
        a2[ks] = *reinterpret_cast<const s16x8*>(&Hs[arow][ks * 32 + lq * 8]);
    float ev[4]; int seg4[4];
#pragma unroll
    for (int j = 0; j < 4; ++j) {
        int r = e0 + wave * 16 + lq * 4 + j;
        ev[j] = evals[r];
        seg4[j] = eb[r] * NN + esrc[r];
    }
#pragma unroll
    for (int nt = 0; nt < 4; ++nt) {
        f32x4 acc = {0.f, 0.f, 0.f, 0.f};
#pragma unroll
        for (int ks = 0; ks < 4; ++ks) {
            s16x8 bf = *reinterpret_cast<const s16x8*>(&W2p[(((nt << 2) + ks) * 64 + lane) * 8]);
            acc = __builtin_amdgcn_mfma_f32_16x16x32_bf16(a2[ks], bf, acc, 0, 0, 0);
        }
        float bias = b2[nt * 16 + lr];
#pragma unroll
        for (int j = 0; j < 4; ++j) {
            float m = (acc[j] + bias) * ev[j];
            atomicAdd(&sums[(size_t)seg4[j] * DM + nt * 16 + lr], m);
        }
    }
}

extern "C" void kernel_launch(void* const* d_in, const int* in_sizes, int n_in,
                              void* d_out, int out_size, void* d_ws, size_t ws_size,
                              hipStream_t stream) {
    const float* node_feats = (const float*)d_in[0];
    const int*   eb    = (const int*)d_in[1];
    const int*   esrc  = (const int*)d_in[2];
    const int*   edst  = (const int*)d_in[3];
    const float* evals = (const float*)d_in[4];
    const float* Wm1 = (const float*)d_in[5];
    const float* bm1 = (const float*)d_in[6];
    const float* Wm2 = (const float*)d_in[7];
    const float* bm2 = (const float*)d_in[8];
    const float* Wu1 = (const float*)d_in[9];
    const float* bu1 = (const float*)d_in[10];
    const float* Wu2 = (const float*)d_in[11];
    const float* bu2 = (const float*)d_in[12];
    float* out = (float*)d_out;
    char* ws = (char*)d_ws;

    const size_t NEED_SLOTS = 30113920;   // slot-based path
    const size_t NEED_SORT  = 22u * 1024 * 1024;
    if (ws_size >= NEED_SLOTS) {
        unsigned short* Qp      = (unsigned short*)(ws);                    // 8 MB
        unsigned short* Pp      = (unsigned short*)(ws + 8388608);          // 8 MB
        unsigned*       payslot = (unsigned*)(ws + 16777216);               // 12 MB (32768*96*4)
        unsigned*       curs    = (unsigned*)(ws + 29360128);               // 128 KB
        unsigned*       ovf_cnt = (unsigned*)(ws + 29491200);               // 128 B
        unsigned*       ovf_seg = (unsigned*)(ws + 29491328);               // 256 KB
        unsigned*       ovf_pay = (unsigned*)(ws + 29753472);               // 256 KB
        unsigned short* Qw      = (unsigned short*)(ws + 30015616);         // 16 KB
        unsigned short* Pw      = (unsigned short*)(ws + 30032000);         // 16 KB
        unsigned short* Wu1p    = (unsigned short*)(ws + 30048384);         // 32 KB
        unsigned short* Wu2p    = (unsigned short*)(ws + 30081152);         // 16 KB
        unsigned short* Wm2p    = (unsigned short*)(ws + 30097536);         // 16 KB

        hipMemsetAsync(curs, 0, 131072 + 128, stream);  // curs + ovf_cnt (contiguous)
        pack_all<<<192, 256, 0, stream>>>(Wm1, Wm2, Wu1, Wu2, Qw, Pw, Wm2p, Wu1p, Wu2p);
        precompute_pq<<<512, 256, 0, stream>>>(node_feats, Qw, Pw, bm1, Qp, Pp);
        scatter_slots<<<NEDGE / 2048, 256, 0, stream>>>(eb, esrc, edst, evals,
                                                        curs, payslot, ovf_cnt, ovf_seg, ovf_pay);
        segment_slots<<<32768 / 16, 256, 0, stream>>>(Qp, Pp, payslot, curs,
                                                      ovf_cnt, ovf_seg, ovf_pay, Wm2p, bm2, out);
        node_kernel<0><<<(NB * NN) / 64, 256, 0, stream>>>(node_feats, out, nullptr,
                                                           Wu1p, bu1, Wu2p, bu2, out);
    } else if (ws_size >= NEED_SORT) {
        unsigned short* Qp   = (unsigned short*)(ws);
        unsigned short* Pp   = (unsigned short*)(ws + 8388608);
        unsigned*       pay  = (unsigned*)(ws + 16777216);
        unsigned*       hist = (unsigned*)(ws + 20971520);
        unsigned*       offs = (unsigned*)(ws + 21102592);
        unsigned*       curs = (unsigned*)(ws + 21233920);
        unsigned short* Qw   = (unsigned short*)(ws + 21364992);
        unsigned short* Pw   = (unsigned short*)(ws + 21381376);
        unsigned short* Wu1p = (unsigned short*)(ws + 21397760);
        unsigned short* Wu2p = (unsigned short*)(ws + 21430528);
        unsigned short* Wm2p = (unsigned short*)(ws + 21446912);

        hipMemsetAsync(hist, 0, 32768 * sizeof(unsigned), stream);
        pack_all<<<192, 256, 0, stream>>>(Wm1, Wm2, Wu1, Wu2, Qw, Pw, Wm2p, Wu1p, Wu2p);
        precompute_pq<<<512, 256, 0, stream>>>(node_feats, Qw, Pw, bm1, Qp, Pp);
        hist_kernel<<<NEDGE / 256, 256, 0, stream>>>(eb, esrc, hist);
        scan_kernel<<<1, 1024, 0, stream>>>(hist, offs, curs);
        scatter_kernel<<<NEDGE / 256, 256, 0, stream>>>(eb, esrc, edst, evals, curs, pay);
        segment_kernel<<<32768 / 16, 256, 0, stream>>>(Qp, Pp, pay, offs, Wm2p, bm2, out);
        node_kernel<0><<<(NB * NN) / 64, 256, 0, stream>>>(node_feats, out, nullptr,
                                                           Wu1p, bu1, Wu2p, bu2, out);
    } else {
        float* counts          = (float*)ws;
        unsigned short* W1p    = (unsigned short*)(ws + 131072);
        unsigned short* W2p    = (unsigned short*)(ws + 163840);
        unsigned short* Wu1p   = (unsigned short*)(ws + 180224);
        unsigned short* Wu2p   = (unsigned short*)(ws + 212992);
        hipMemsetAsync(d_out, 0, (size_t)out_size * sizeof(float), stream);
        hipMemsetAsync(counts, 0, 32768 * sizeof(float), stream);
        pack_weights<<<64, 256, 0, stream>>>(Wm1, W1p, 128, 128);
        pack_weights<<<32, 256, 0, stream>>>(Wm2, W2p, 128, 64);
        pack_weights<<<64, 256, 0, stream>>>(Wu1, Wu1p, 128, 128);
        pack_weights<<<32, 256, 0, stream>>>(Wu2, Wu2p, 128, 64);
        edge_kernel<<<NEDGE / 64, 256, 0, stream>>>(node_feats, eb, esrc, edst, evals,
                                                    W1p, bm1, W2p, bm2, out, counts);
        node_kernel<1><<<(NB * NN) / 64, 256, 0, stream>>>(node_feats, out, counts,
                                                           Wu1p, bu1, Wu2p, bu2, out);
    }
}